// Round 12
// baseline (4684.438 us; speedup 1.0000x reference)
//
#include <hip/hip_runtime.h>
#include <cmath>

typedef float v2f __attribute__((ext_vector_type(2)));
typedef float v4f __attribute__((ext_vector_type(4)));

__device__ __forceinline__ float sigm(float x) { return 1.0f / (1.0f + __expf(-x)); }

// ---------------- tiled transpose [2048][K] -> [K][2048] ----------------
__global__ __launch_bounds__(256) void transpose_w(const float* __restrict__ in,
                                                   float* __restrict__ outT, int K) {
  __shared__ float tile[32][33];
  int tx = threadIdx.x & 31, ty = threadIdx.x >> 5;
  int k0 = blockIdx.x * 32;
  int j0 = blockIdx.y * 32;
#pragma unroll
  for (int i = 0; i < 32; i += 8)
    tile[ty + i][tx] = in[(size_t)(j0 + ty + i) * K + k0 + tx];
  __syncthreads();
#pragma unroll
  for (int i = 0; i < 32; i += 8)
    outT[(size_t)(k0 + ty + i) * 2048 + j0 + tx] = tile[tx][ty + i];
}

// one j-slice of the gate GEMV — per-accumulator FMA chains identical to R5/R7
// (numerics PINNED: R6 failed on chain reorder). Packed v2f: acc pair (2p,2p+1)
// computed by v_pk_fma_f32, each half the exact same scalar chain.
__device__ __forceinline__ void gemv_j(const v4f* __restrict__ A4,
                                       const v4f* __restrict__ W4, int j, int kqx,
                                       int kq, int jlo, int jhi, int b0, int b1,
                                       v2f (&o0)[4], v2f (&o1)[4]) {
  int qa = (j << 3) + kqx;
  v4f a04 = A4[b0 * 192 + qa];
  v4f a14 = A4[b1 * 192 + qa];
  int wr = ((j << 3) + kq) << 2;
#pragma unroll
  for (int i = 0; i < 4; ++i) {
    v4f wlo = W4[(wr + i) * 8 + jlo];
    v4f whi = W4[(wr + i) * 8 + jhi];
    v2f a0; a0[0] = a04[i]; a0[1] = a04[i];
    v2f a1; a1[0] = a14[i]; a1[1] = a14[i];
    o0[0] = __builtin_elementwise_fma(a0, wlo.lo, o0[0]);
    o0[1] = __builtin_elementwise_fma(a0, wlo.hi, o0[1]);
    o0[2] = __builtin_elementwise_fma(a0, whi.lo, o0[2]);
    o0[3] = __builtin_elementwise_fma(a0, whi.hi, o0[3]);
    o1[0] = __builtin_elementwise_fma(a1, wlo.lo, o1[0]);
    o1[1] = __builtin_elementwise_fma(a1, wlo.hi, o1[1]);
    o1[2] = __builtin_elementwise_fma(a1, whi.lo, o1[2]);
    o1[3] = __builtin_elementwise_fma(a1, whi.hi, o1[3]);
  }
}

// ---- persistent fused LSTM chain: 256 steps in one cooperative launch ----
// Structure = R7/R11 (best measured). Barrier lore (R8-R10): per-block flag on
// own 128B line set by tid0 after block-wide drain+sync; wave0 alone polls all
// 64 flags lane-parallel; x-staging in the flag shadow; full-block COALESCED
// h restage. GEMV now packed (v_pk_fma_f32) — bit-exact chains.
__global__ __launch_bounds__(256, 1) void lstm_chain(
    const float* __restrict__ WT, const float* __restrict__ x,
    const float* __restrict__ bih, const float* __restrict__ bhh,
    float* __restrict__ HBUF,        // [256][64][512]
    float* __restrict__ Cst,         // [64][512]
    unsigned int* __restrict__ flg,  // 4 dom x 64 flags x 32 uints
    int is_enc) {
  extern __shared__ float lds[];
  v4f* W4 = (v4f*)lds;            // 768 x 8 f4 (XOR-swizzled) = 96 KB
  v4f* A4 = (v4f*)(lds + 24576);  // 16 x 192 f4 (XOR-swizzled) = 48 KB
  float* gates = lds + 24576 + 12288;  // 16 x 40
  const int bg = blockIdx.x >> 6, ng = blockIdx.x & 63;
  const int tid = threadIdx.x;
  unsigned int* myflag = flg + (size_t)(bg * 64 + ng) * 32;
  unsigned int* dom = flg + (size_t)bg * 64 * 32;

  // ---- stage W slice once ----
#pragma unroll
  for (int r = 0; r < 24; ++r) {
    int idx = tid + 256 * r;
    int k = idx >> 3, j = idx & 7;
    v4f v =
        *(const v4f*)(WT + (size_t)k * 2048 + (j >> 1) * 512 + ng * 8 + (j & 1) * 4);
    W4[k * 8 + (j ^ ((k >> 2) & 7))] = v;
  }
  // ---- per-thread cell state + biases (threads 0..127 own (b,n8)) ----
  float bi_i = 0.f, bi_f = 0.f, bi_g = 0.f, bi_o = 0.f, creg = 0.f;
  if (tid < 128) {
    int b = tid >> 3, n8 = tid & 7;
    int n_g = ng * 8 + n8;
    bi_i = bih[n_g] + bhh[n_g];
    bi_f = bih[512 + n_g] + bhh[512 + n_g];
    bi_g = bih[1024 + n_g] + bhh[1024 + n_g];
    bi_o = bih[1536 + n_g] + bhh[1536 + n_g];
    if (!is_enc) creg = Cst[(size_t)(bg * 16 + b) * 512 + n_g];
  }
  // ---- initial A-h: h0 (zeros for encoder, HBUF row 255 for decoder) ----
#pragma unroll
  for (int r = 0; r < 8; ++r) {
    int idx = tid + 256 * r;
    int b = idx >> 7, q = idx & 127;
    v4f v;
    if (is_enc) {
      v = (v4f){0.f, 0.f, 0.f, 0.f};
    } else {
      v = *(const v4f*)(HBUF + ((size_t)(255 * 64) + bg * 16 + b) * 512 + 4 * q);
    }
    A4[b * 192 + (q ^ ((b >> 1) & 7))] = v;
  }
  // ---- initial A-x: x_0 ----
#pragma unroll
  for (int r = 0; r < 4; ++r) {
    int idx = tid + 256 * r;
    int b = idx >> 6, q = idx & 63;
    v4f v = *(const v4f*)(x + ((size_t)(bg * 16 + b) * 256 + 0) * 256 + 4 * q);
    A4[b * 192 + ((128 + q) ^ ((b >> 1) & 7))] = v;
  }
  __syncthreads();

  const int w = tid >> 6;  // wave = gate (0:i 1:f 2:g 3:o)
  const int lane = tid & 63;
  const int kq = lane >> 3, b8 = lane & 7;
  const int b0 = 2 * b8, b1 = b0 + 1;
  const int jlo = (2 * w) ^ kq, jhi = jlo ^ 1;
  const int kqx = kq ^ b8;

  for (int t = 0; t < 256; ++t) {
    v2f acc0[4], acc1[4];
#pragma unroll
    for (int p = 0; p < 4; ++p) {
      acc0[p] = (v2f){0.f, 0.f};
      acc1[p] = (v2f){0.f, 0.f};
    }
#pragma unroll 2
    for (int j = 0; j < 24; ++j)  // full K=768 chain, pinned order
      gemv_j(A4, W4, j, kqx, kq, jlo, jhi, b0, b1, acc0, acc1);
    // reduce over kq (lane-stride 8,16,32) — pinned partners/order
#pragma unroll
    for (int d = 8; d <= 32; d <<= 1) {
#pragma unroll
      for (int p = 0; p < 4; ++p) {
        acc0[p][0] += __shfl_xor(acc0[p][0], d, 64);
        acc0[p][1] += __shfl_xor(acc0[p][1], d, 64);
        acc1[p][0] += __shfl_xor(acc1[p][0], d, 64);
        acc1[p][1] += __shfl_xor(acc1[p][1], d, 64);
      }
    }
    if (kq == 0) {
#pragma unroll
      for (int p = 0; p < 4; ++p) {
        gates[b0 * 40 + w * 8 + 2 * p] = acc0[p][0];
        gates[b0 * 40 + w * 8 + 2 * p + 1] = acc0[p][1];
        gates[b1 * 40 + w * 8 + 2 * p] = acc1[p][0];
        gates[b1 * 40 + w * 8 + 2 * p + 1] = acc1[p][1];
      }
    }
    __syncthreads();
    // ---- cell update + h store (agent-scope write-through, no fence) ----
    if (tid < 128) {
      int bb = tid >> 3, n8 = tid & 7;
      float pi = gates[bb * 40 + n8] + bi_i;
      float pf = gates[bb * 40 + 8 + n8] + bi_f;
      float pg = gates[bb * 40 + 16 + n8] + bi_g;
      float po = gates[bb * 40 + 24 + n8] + bi_o;
      float ig = sigm(pi), fg = sigm(pf), gg = tanhf(pg), og = sigm(po);
      float cn = fmaf(fg, creg, ig * gg);
      if (is_enc) creg = cn;  // decoder: cell pinned at cT
      float hn = og * tanhf(cn);
      float* hp = HBUF + ((size_t)t * 64 + bg * 16 + bb) * 512 + ng * 8 + n8;
      __hip_atomic_store(hp, hn, __ATOMIC_RELAXED, __HIP_MEMORY_SCOPE_AGENT);
      if (is_enc && t == 255) Cst[(size_t)(bg * 16 + bb) * 512 + ng * 8 + n8] = cn;
    }
    if (t == 255) break;
    // all h of this block at the coherent point before the flag store
    asm volatile("s_waitcnt vmcnt(0)" ::: "memory");
    __syncthreads();
    if (tid == 0)
      __hip_atomic_store(myflag, (unsigned)(t + 1), __ATOMIC_RELAXED,
                         __HIP_MEMORY_SCOPE_AGENT);
    asm volatile("" ::: "memory");  // keep the flag store ahead of the staging
    // ---- stage x_{t+1} (cached, flag-independent) — shadows flag latency ----
#pragma unroll
    for (int r = 0; r < 4; ++r) {
      int idx = tid + 256 * r;
      int bb = idx >> 6, q = idx & 63;
      v4f v =
          *(const v4f*)(x + ((size_t)(bg * 16 + bb) * 256 + (t + 1)) * 256 + 4 * q);
      A4[bb * 192 + ((128 + q) ^ ((bb >> 1) & 7))] = v;
    }
    // ---- wave 0: poll all 64 producer flags lane-parallel ----
    if (tid < 64) {
      const unsigned tgt = (unsigned)(t + 1);
      unsigned int* fp = dom + (size_t)tid * 32;
      while (true) {
        unsigned v = __hip_atomic_load(fp, __ATOMIC_RELAXED, __HIP_MEMORY_SCOPE_AGENT);
        if (__all((int)(v >= tgt))) break;
        __builtin_amdgcn_s_sleep(1);
      }
    }
    __syncthreads();
    // ---- h restage: full-block coalesced (consecutive-lane 16B loads) ----
    const v4f* hb = (const v4f*)(HBUF + (size_t)t * 64 * 512);
#pragma unroll
    for (int r = 0; r < 8; ++r) {
      int idx = tid + 256 * r;
      int bb = idx >> 7, q = idx & 127;
      v4f v = hb[(size_t)(bg * 16 + bb) * 128 + q];
      A4[bb * 192 + (q ^ ((bb >> 1) & 7))] = v;
    }
    __syncthreads();
  }
}

// ---- GEMM: C[r,n] = sum_k A[r][k] * W[n,k] ; 128x128 tile, 8x8 micro ----
__global__ __launch_bounds__(256) void gemm_fp32(const float* __restrict__ A,
                                                 const float* __restrict__ W,
                                                 float* __restrict__ C, int N, int K) {
  __shared__ float As[16 * 132];
  __shared__ float Ws[16 * 132];
  int tid = threadIdx.x;
  int n0 = blockIdx.x * 128, m0 = blockIdx.y * 128;
  int row = tid >> 1;
  int kbase = (tid & 1) * 8;
  const float* ap = A + (size_t)(m0 + row) * K;
  const float* wp = W + (size_t)(n0 + row) * K;
  int ty = tid >> 4, tx = tid & 15;
  float acc[8][8];
#pragma unroll
  for (int i = 0; i < 8; ++i)
#pragma unroll
    for (int j = 0; j < 8; ++j) acc[i][j] = 0.f;

  for (int kt = 0; kt < K; kt += 16) {
    float4 va0 = *(const float4*)(ap + kt + kbase);
    float4 va1 = *(const float4*)(ap + kt + kbase + 4);
    float4 vw0 = *(const float4*)(wp + kt + kbase);
    float4 vw1 = *(const float4*)(wp + kt + kbase + 4);
    __syncthreads();
    As[(kbase + 0) * 132 + row] = va0.x;
    As[(kbase + 1) * 132 + row] = va0.y;
    As[(kbase + 2) * 132 + row] = va0.z;
    As[(kbase + 3) * 132 + row] = va0.w;
    As[(kbase + 4) * 132 + row] = va1.x;
    As[(kbase + 5) * 132 + row] = va1.y;
    As[(kbase + 6) * 132 + row] = va1.z;
    As[(kbase + 7) * 132 + row] = va1.w;
    Ws[(kbase + 0) * 132 + row] = vw0.x;
    Ws[(kbase + 1) * 132 + row] = vw0.y;
    Ws[(kbase + 2) * 132 + row] = vw0.z;
    Ws[(kbase + 3) * 132 + row] = vw0.w;
    Ws[(kbase + 4) * 132 + row] = vw1.x;
    Ws[(kbase + 5) * 132 + row] = vw1.y;
    Ws[(kbase + 6) * 132 + row] = vw1.z;
    Ws[(kbase + 7) * 132 + row] = vw1.w;
    __syncthreads();
#pragma unroll
    for (int kk = 0; kk < 16; ++kk) {
      float4 a0 = *(const float4*)&As[kk * 132 + ty * 8];
      float4 a1 = *(const float4*)&As[kk * 132 + ty * 8 + 4];
      float4 w0 = *(const float4*)&Ws[kk * 132 + tx * 8];
      float4 w1 = *(const float4*)&Ws[kk * 132 + tx * 8 + 4];
      float av[8] = {a0.x, a0.y, a0.z, a0.w, a1.x, a1.y, a1.z, a1.w};
      float wv[8] = {w0.x, w0.y, w0.z, w0.w, w1.x, w1.y, w1.z, w1.w};
#pragma unroll
      for (int i = 0; i < 8; ++i)
#pragma unroll
        for (int j = 0; j < 8; ++j) acc[i][j] = fmaf(av[i], wv[j], acc[i][j]);
    }
  }
#pragma unroll
  for (int i = 0; i < 8; ++i) {
    float* cp = C + (size_t)(m0 + ty * 8 + i) * N + n0 + tx * 8;
    *(float4*)cp = make_float4(acc[i][0], acc[i][1], acc[i][2], acc[i][3]);
    *(float4*)(cp + 4) = make_float4(acc[i][4], acc[i][5], acc[i][6], acc[i][7]);
  }
}

// ---- scorer: out[b,t,s] = sum_w vt[w]*tanh(e1[s,b,w] + H2[t,b,w]) ----
// 512 threads: waves 0-3 sum w in [0,256), waves 4-7 sum [256,512); merged
// lo+hi via LDS (deterministic 2-term add; non-recurrent, no amplification).
// Same 67KB LDS -> 2 blocks/CU but 16 waves/CU for transcendental hiding.
__global__ __launch_bounds__(512) void scorer(const float* __restrict__ E1,
                                              const float* __restrict__ H2,
                                              const float* __restrict__ vt,
                                              float* __restrict__ out) {
  extern __shared__ float smem[];
  float* e1s = smem;          // 16 x 516
  float* h2s = smem + 8256;   // 16 x 516
  float* red = smem + 16512;  // 256
  int tid = threadIdx.x;
  int sx = blockIdx.x;
  int b = blockIdx.y;
  int tt = blockIdx.z;
#pragma unroll
  for (int j = 0; j < 4; ++j) {
    int idx = tid + 512 * j;
    int r = idx >> 7, c4 = idx & 127;
    float4 v = *(const float4*)(E1 + ((size_t)(sx * 16 + r) * 64 + b) * 512 + c4 * 4);
    *(float4*)&e1s[r * 516 + c4 * 4] = v;
    float4 h = *(const float4*)(H2 + ((size_t)(tt * 16 + r) * 64 + b) * 512 + c4 * 4);
    *(float4*)&h2s[r * 516 + c4 * 4] = h;
  }
  __syncthreads();
  int half = tid >> 8;  // 0: w4 0..63, 1: w4 64..127
  int lid = tid & 255;
  int tl = lid >> 4, sl = lid & 15;
  float acc = 0.f;
  const float* ep = &e1s[sl * 516 + half * 256];
  const float* hp = &h2s[tl * 516 + half * 256];
  const float* vp = vt + half * 256;
#pragma unroll 8
  for (int w4 = 0; w4 < 64; ++w4) {
    float4 a = *(const float4*)(ep + w4 * 4);
    float4 h = *(const float4*)(hp + w4 * 4);
    float4 vv = *(const float4*)(vp + w4 * 4);
    float x0 = a.x + h.x, x1 = a.y + h.y, x2 = a.z + h.z, x3 = a.w + h.w;
    float t0 = fmaf(-2.f, __builtin_amdgcn_rcpf(__expf(x0 + x0) + 1.f), 1.f);
    float t1 = fmaf(-2.f, __builtin_amdgcn_rcpf(__expf(x1 + x1) + 1.f), 1.f);
    float t2 = fmaf(-2.f, __builtin_amdgcn_rcpf(__expf(x2 + x2) + 1.f), 1.f);
    float t3 = fmaf(-2.f, __builtin_amdgcn_rcpf(__expf(x3 + x3) + 1.f), 1.f);
    acc = fmaf(t0, vv.x, acc);
    acc = fmaf(t1, vv.y, acc);
    acc = fmaf(t2, vv.z, acc);
    acc = fmaf(t3, vv.w, acc);
  }
  if (half) red[lid] = acc;
  __syncthreads();
  if (!half)
    out[((size_t)b * 256 + tt * 16 + tl) * 256 + sx * 16 + sl] = acc + red[lid];
}

// ---- in-place log_softmax over rows of 256 ----
__global__ __launch_bounds__(256) void logsoftmax_kernel(float* __restrict__ out) {
  __shared__ float red[256];
  int tid = threadIdx.x;
  float* row = out + (size_t)blockIdx.x * 256;
  float v = row[tid];
  red[tid] = v;
  __syncthreads();
  for (int off = 128; off > 0; off >>= 1) {
    if (tid < off) red[tid] = fmaxf(red[tid], red[tid + off]);
    __syncthreads();
  }
  float mx = red[0];
  __syncthreads();
  red[tid] = __expf(v - mx);
  __syncthreads();
  for (int off = 128; off > 0; off >>= 1) {
    if (tid < off) red[tid] += red[tid + off];
    __syncthreads();
  }
  float lse = logf(red[0]);
  row[tid] = v - mx - lse;
}

extern "C" void kernel_launch(void* const* d_in, const int* in_sizes, int n_in,
                              void* d_out, int out_size, void* d_ws, size_t ws_size,
                              hipStream_t stream) {
  (void)in_sizes; (void)n_in; (void)out_size; (void)ws_size;
  const float* x = (const float*)d_in[0];
  const float* eWih = (const float*)d_in[1];
  const float* eWhh = (const float*)d_in[2];
  const float* ebih = (const float*)d_in[3];
  const float* ebhh = (const float*)d_in[4];
  const float* dWih = (const float*)d_in[5];
  const float* dWhh = (const float*)d_in[6];
  const float* dbih = (const float*)d_in[7];
  const float* dbhh = (const float*)d_in[8];
  const float* w1 = (const float*)d_in[9];
  const float* w2 = (const float*)d_in[10];
  const float* vt = (const float*)d_in[11];
  float* out = (float*)d_out;
  float* ws = (float*)d_ws;

  // workspace (floats) — ~113.5 MB
  float* E1 = ws;                  //  8,388,608  [S,B,W]
  float* H2 = E1 + 8388608ull;     //  8,388,608  [S,B,W]
  float* HBUF = H2 + 8388608ull;   //  8,388,608  [S,B,H] enc then dec h
  float* WTe = HBUF + 8388608ull;  //  1,572,864  [768][2048]
  float* WTd = WTe + 1572864ull;   //  1,572,864
  float* Cst = WTd + 1572864ull;   //     32,768
  unsigned int* FLG = (unsigned int*)(Cst + 32768ull);  // 2 x 8192 uints

  const unsigned ldsB = (24576 + 12288 + 640) * 4;       // 150,016 B
  const unsigned scorerLds = (2 * 16 * 516 + 256) * 4;   // 67,072 B

  hipMemsetAsync(FLG, 0, 16384 * sizeof(unsigned int), stream);
  transpose_w<<<dim3(16, 64), 256, 0, stream>>>(eWhh, WTe, 512);
  transpose_w<<<dim3(8, 64), 256, 0, stream>>>(eWih, WTe + 512 * 2048, 256);
  transpose_w<<<dim3(16, 64), 256, 0, stream>>>(dWhh, WTd, 512);
  transpose_w<<<dim3(8, 64), 256, 0, stream>>>(dWih, WTd + 512 * 2048, 256);

  {  // encoder chain
    const float* a0 = WTe; const float* a1 = x; const float* a2 = ebih;
    const float* a3 = ebhh; float* a4 = HBUF; float* a5 = Cst;
    unsigned int* a6 = FLG; int a7 = 1;
    void* args[] = {&a0, &a1, &a2, &a3, &a4, &a5, &a6, &a7};
    hipLaunchCooperativeKernel((const void*)lstm_chain, dim3(256), dim3(256), args,
                               ldsB, stream);
  }
  gemm_fp32<<<dim3(4, 128), 256, 0, stream>>>(HBUF, w1, E1, 512, 512);
  {  // decoder chain
    const float* a0 = WTd; const float* a1 = x; const float* a2 = dbih;
    const float* a3 = dbhh; float* a4 = HBUF; float* a5 = Cst;
    unsigned int* a6 = FLG + 8192; int a7 = 0;
    void* args[] = {&a0, &a1, &a2, &a3, &a4, &a5, &a6, &a7};
    hipLaunchCooperativeKernel((const void*)lstm_chain, dim3(256), dim3(256), args,
                               ldsB, stream);
  }
  gemm_fp32<<<dim3(4, 128), 256, 0, stream>>>(HBUF, w2, H2, 512, 512);
  scorer<<<dim3(16, 64, 16), 512, scorerLds, stream>>>(E1, H2, vt, out);
  logsoftmax_kernel<<<16384, 256, 0, stream>>>(out);
}